// Round 10
// baseline (392.569 us; speedup 1.0000x reference)
//
#include <hip/hip_runtime.h>
#include <hip/hip_cooperative_groups.h>

namespace cg = cooperative_groups;

typedef unsigned short u16;
typedef unsigned int   u32;

// RESOLVED (rounds 0-10): d_out is FLOAT32. Inputs f32. din=128, hd=128
// (H=2, dout=64), N=in_sizes[0]/128, NE=in_sizes[1]/2.
// Outputs flat f32: H_out [0,N*64) ; E [N*64,+2NE) ; attr [+NE).
// R17: fp16 (absmax .0156). R19: bucket scatter, 219. R20: LB8 regressed
//      (L2 thrash). R21: phase-fused gemm_scatter = 80us but occ 27%
//      (51KB LDS strangled scatter TLP); kernel sum 145 vs total 216 ->
//      ~60-70us is LAUNCH GAPS (~15-20us each, consistent R13-R21).
// R22: ONE persistent cooperative kernel, grid.sync between phases:
//      (0) prep; (1) GEMM tiles + scatter + passthrough with ALTERNATING
//      block roles (half gemm-first, half scatter-first -> heterogeneous
//      overlap at full occupancy); (2) edge_fused grid-strided.
//      W^T read from GLOBAL (32KB, L1-resident) -> LDS only 18.4KB union
//      -> high occupancy for every phase, sW bank conflicts gone.
//      Fallback to 3 plain launches (same device code) if coop fails.

#define DIN   128
#define DOUT  64
#define HD    128   // H * DOUT
#define BCAP  64    // bucket capacity per node

typedef __attribute__((ext_vector_type(8))) _Float16 f16x8;
typedef __attribute__((ext_vector_type(2))) _Float16 h2;
typedef __attribute__((ext_vector_type(4))) float    f32x4;

union H2U { u32 u; h2 h; };
__device__ __forceinline__ h2  U2H(u32 u) { H2U x; x.u = u; return x.h; }
__device__ __forceinline__ u32 H2Ub(h2 h) { H2U x; x.h = h; return x.u; }

__device__ __forceinline__ u16 f2h(float f) {
    _Float16 h = (_Float16)f;              // RNE
    u16 r; __builtin_memcpy(&r, &h, 2); return r;
}

// packed fp16 max via ISA (v_pk_max_f16 is VOP3P, present on gfx950)
__device__ __forceinline__ u32 pkmax(u32 a, u32 b) {
    u32 d;
    asm("v_pk_max_f16 %0, %1, %2" : "=v"(d) : "v"(a), "v"(b));
    return d;
}

__device__ __forceinline__ float fdot2f(h2 a, h2 b, float c) {
#if __has_builtin(__builtin_amdgcn_fdot2)
    return __builtin_amdgcn_fdot2(a, b, c, false);
#else
    return c + (float)a[0] * (float)b[0] + (float)a[1] * (float)b[1];
#endif
}

union SharedU {
    u16 sX[64 * 136];                               // 17408 B (gemm)
    struct { uint4 sWp[1024]; u32 sAggU[8 * 64]; } ef;  // 18432 B (edge)
};

// ---------------------------------------------------------------------------
// phase-0 item: zero count + WT transpose->fp16 + Wfp pack
// ---------------------------------------------------------------------------
__device__ __forceinline__ void dev_prep_item(
    int i, const float* __restrict__ Wl, const float* __restrict__ Wr,
    const float* __restrict__ Wf, u16* __restrict__ WTl, u16* __restrict__ WTr,
    uint4* __restrict__ Wfp, int* __restrict__ count, int N)
{
    if (i < N) { count[i] = 0; return; }
    int j = i - N;
    if (j < 16384) {
        int k = j >> 7, c = j & 127;
        WTl[c * 128 + k] = f2h(Wl[j]);
    } else if (j < 32768) {
        int t = j - 16384;
        int k = t >> 7, c = t & 127;
        WTr[c * 128 + k] = f2h(Wr[t]);
    } else if (j < 33792) {
        int t = j - 32768;
        int k4 = t >> 5, c = t & 31;
        const float* wrow = Wf + (size_t)(4 * k4) * DOUT;
        u32 a0 = (u32)f2h(wrow[c])              | ((u32)f2h(wrow[DOUT + c]) << 16);
        u32 a1 = (u32)f2h(wrow[2 * DOUT + c])   | ((u32)f2h(wrow[3 * DOUT + c]) << 16);
        u32 a2 = (u32)f2h(wrow[c + 32])         | ((u32)f2h(wrow[DOUT + c + 32]) << 16);
        u32 a3 = (u32)f2h(wrow[2 * DOUT + c + 32]) | ((u32)f2h(wrow[3 * DOUT + c + 32]) << 16);
        Wfp[t] = make_uint4(a0, a1, a2, a3);
    }
}

__device__ __forceinline__ void dev_scatter_edge(
    int e, const int* __restrict__ E, int* __restrict__ count,
    u16* __restrict__ bucket, int N, int NE)
{
    int src = E[e];
    int dst = E[NE + e];
    if ((u32)dst >= (u32)N) dst = 0;
    if ((u32)src >= (u32)N) src = 0;
    int rank = atomicAdd(&count[dst], 1);
    if (rank < BCAP) bucket[(size_t)dst * BCAP + rank] = (u16)src;
}

__device__ __forceinline__ void dev_pass_item(
    int p, const int* __restrict__ E, const float* __restrict__ attr,
    float* __restrict__ out, size_t base, int NE)
{
    if (p < 2 * NE) out[base + p] = (float)E[p];
    else            out[base + p] = attr[p - 2 * NE];
}

// ---------------------------------------------------------------------------
// GEMM tile: dst = f16(X @ W + b), dst[node*128+c]; A=W^T from GLOBAL
// (32KB, L1-hot), B=X from LDS -> D col=node, row=c -> packed uint2 stores.
// ---------------------------------------------------------------------------
__device__ __forceinline__ void dev_gemm_tile(
    int bt, int tid, u16* sX,
    const float* __restrict__ X,
    const u16* __restrict__ WTl, const float* __restrict__ bl,
    const u16* __restrict__ WTr, const float* __restrict__ br,
    u16* __restrict__ xl_p, u16* __restrict__ xr_p, int N)
{
    const int cb   = bt & 1;
    const int row0 = (bt >> 1) * 64;
    const u16*   WT  = cb ? WTr : WTl;
    const float* bia = cb ? br : bl;

    __syncthreads();   // previous users of sX done
    for (int idx = tid; idx < 64 * 32; idx += 256) {
        int r  = idx >> 5;
        int k4 = (idx & 31) << 2;
        int gr = row0 + r;
        float4 v = make_float4(0.f, 0.f, 0.f, 0.f);
        if (gr < N) v = *(const float4*)(X + (size_t)gr * DIN + k4);
        u32 p0 = (u32)f2h(v.x) | ((u32)f2h(v.y) << 16);
        u32 p1 = (u32)f2h(v.z) | ((u32)f2h(v.w) << 16);
        *(uint2*)&sX[r * 136 + k4] = make_uint2(p0, p1);
    }
    __syncthreads();

    const int wv   = tid >> 6;
    const int lane = tid & 63;
    const int m    = lane & 15;
    const int quad = lane >> 4;

    f32x4 acc[8] = {};
    #pragma unroll
    for (int kc = 0; kc < 4; kc++) {
        f16x8 bx = *(const f16x8*)&sX[(wv * 16 + m) * 136 + kc * 32 + quad * 8];
        #pragma unroll
        for (int t = 0; t < 8; t++) {
            f16x8 aw = *(const f16x8*)&WT[(t * 16 + m) * 128 + kc * 32 + quad * 8];
            acc[t] = __builtin_amdgcn_mfma_f32_16x16x32_f16(aw, bx, acc[t], 0, 0, 0);
        }
    }

    const int gn = row0 + wv * 16 + m;          // node (D col = lane&15)
    if (gn < N) {
        u16* dst = cb ? xr_p : xl_p;
        #pragma unroll
        for (int t = 0; t < 8; t++) {
            const int c0 = t * 16 + quad * 4;   // D row = quad*4+r
            float4 bv = *(const float4*)(bia + c0);
            u32 p0 = (u32)f2h(acc[t][0] + bv.x) | ((u32)f2h(acc[t][1] + bv.y) << 16);
            u32 p1 = (u32)f2h(acc[t][2] + bv.z) | ((u32)f2h(acc[t][3] + bv.w) << 16);
            *(uint2*)(dst + (size_t)gn * HD + c0) = make_uint2(p0, p1);
        }
    }
}

// ---------------------------------------------------------------------------
// edge_fused group (8 nodes): one node per 32-lane half; two 16-lane
// subgroups each own one edge per slot.  Lane owns 8 channels (uint4
// gather); dot = fdot2 + 3 xor steps; packed fp16 leaky/accumulate.
// Depth 8/4/2 + masked pair tail.  Virtual self loop past cnt_b.
// ---------------------------------------------------------------------------
template<int D>
__device__ __forceinline__ void edge_block(
    int myidx, int j, int sgbase, const char* xbase,
    const h2* xr2, const h2* at2, h2 c02,
    h2* acc2, float& lden)
{
    uint4 q[D];
    #pragma unroll
    for (int b = 0; b < D; b++) {
        u32 off = (u32)__shfl(myidx, sgbase + j + 2 * b) << 8;
        q[b] = *(const uint4*)(xbase + off);
    }
    float sh[D];
    #pragma unroll
    for (int b = 0; b < D; b++) {
        h2 v0 = U2H(q[b].x) + xr2[0];
        h2 v1 = U2H(q[b].y) + xr2[1];
        h2 v2 = U2H(q[b].z) + xr2[2];
        h2 v3 = U2H(q[b].w) + xr2[3];
        v0 = U2H(pkmax(H2Ub(v0), H2Ub(v0 * c02)));
        v1 = U2H(pkmax(H2Ub(v1), H2Ub(v1 * c02)));
        v2 = U2H(pkmax(H2Ub(v2), H2Ub(v2 * c02)));
        v3 = U2H(pkmax(H2Ub(v3), H2Ub(v3 * c02)));
        float s = fdot2f(v0, at2[0], 0.f);
        s = fdot2f(v1, at2[1], s);
        s = fdot2f(v2, at2[2], s);
        s = fdot2f(v3, at2[3], s);
        sh[b] = s;
    }
    #pragma unroll
    for (int m = 4; m; m >>= 1) {
        #pragma unroll
        for (int b = 0; b < D; b++) sh[b] += __shfl_xor(sh[b], m);
    }
    #pragma unroll
    for (int b = 0; b < D; b++) {
        float p = exp2f(sh[b]);
        lden += p;
        _Float16 ph = (_Float16)p;
        h2 p2 = {ph, ph};
        acc2[0] += p2 * U2H(q[b].x);
        acc2[1] += p2 * U2H(q[b].y);
        acc2[2] += p2 * U2H(q[b].z);
        acc2[3] += p2 * U2H(q[b].w);
    }
}

__device__ __forceinline__ void dev_edge_group(
    int g, int tid, const uint4* sWp, u32* sAggU,
    const u16* __restrict__ xl_p, const u16* __restrict__ xr_p,
    const float* __restrict__ att, const float* __restrict__ bias,
    const float* __restrict__ bf, const float* __restrict__ gamma,
    const float* __restrict__ beta, const int* __restrict__ count,
    const u16* __restrict__ bucket, float* __restrict__ out, int N)
{
    const int l      = tid & 63;
    const int half   = tid >> 5;
    const int hl     = tid & 31;
    const int g16    = l & 15;
    const int ch0    = g16 * 8;
    const int sgsel  = (l >> 4) & 1;
    const int sgbase = (l & 32) + sgsel;
    const int n      = g * 8 + half;
    const bool active = (n < N);

    const h2 c02 = {(_Float16)0.2f, (_Float16)0.2f};
    h2 at2[4], xr2[4];
    {
        const float L2E = 1.44269504f;
        float4 a0 = *(const float4*)(att + ch0);
        float4 a1 = *(const float4*)(att + ch0 + 4);
        at2[0] = h2{(_Float16)(a0.x * L2E), (_Float16)(a0.y * L2E)};
        at2[1] = h2{(_Float16)(a0.z * L2E), (_Float16)(a0.w * L2E)};
        at2[2] = h2{(_Float16)(a1.x * L2E), (_Float16)(a1.y * L2E)};
        at2[3] = h2{(_Float16)(a1.z * L2E), (_Float16)(a1.w * L2E)};
        uint4 pr = make_uint4(0, 0, 0, 0);
        if (active) pr = *(const uint4*)(xr_p + (size_t)n * HD + ch0);
        xr2[0] = U2H(pr.x); xr2[1] = U2H(pr.y);
        xr2[2] = U2H(pr.z); xr2[3] = U2H(pr.w);
    }

    h2 acc2[4] = {};
    float lden = 0.f;

    int cnt_b = 0;
    if (active) {
        cnt_b = count[n];
        if (cnt_b < 0) cnt_b = 0;
        if (cnt_b > BCAP) cnt_b = BCAP;
    }
    const int cnt = active ? cnt_b + 1 : 0;   // + virtual self loop
    const u16* mybkt = bucket + (size_t)(active ? n : 0) * BCAP;

    const char* xbase = (const char*)xl_p + ch0 * 2;

    int done = 0;
    while (done < cnt) {
        int chunk = cnt - done; if (chunk > 32) chunk = 32;
        int myidx = 0;
        if (hl < chunk) {
            int gj = done + hl;
            myidx = (gj < cnt_b) ? (int)mybkt[gj] : n;
        }
        int j = 0;
        for (; j + 16 <= chunk; j += 16)
            edge_block<8>(myidx, j, sgbase, xbase, xr2, at2, c02, acc2, lden);
        if (j + 8 <= chunk) {
            edge_block<4>(myidx, j, sgbase, xbase, xr2, at2, c02, acc2, lden);
            j += 8;
        }
        if (j + 4 <= chunk) {
            edge_block<2>(myidx, j, sgbase, xbase, xr2, at2, c02, acc2, lden);
            j += 4;
        }
        for (; j < chunk; j += 2) {
            u32 off = (u32)__shfl(myidx, sgbase + j) << 8;
            uint4 q = *(const uint4*)(xbase + off);
            h2 v0 = U2H(q.x) + xr2[0];
            h2 v1 = U2H(q.y) + xr2[1];
            h2 v2 = U2H(q.z) + xr2[2];
            h2 v3 = U2H(q.w) + xr2[3];
            v0 = U2H(pkmax(H2Ub(v0), H2Ub(v0 * c02)));
            v1 = U2H(pkmax(H2Ub(v1), H2Ub(v1 * c02)));
            v2 = U2H(pkmax(H2Ub(v2), H2Ub(v2 * c02)));
            v3 = U2H(pkmax(H2Ub(v3), H2Ub(v3 * c02)));
            float s = fdot2f(v0, at2[0], 0.f);
            s = fdot2f(v1, at2[1], s);
            s = fdot2f(v2, at2[2], s);
            s = fdot2f(v3, at2[3], s);
            #pragma unroll
            for (int m = 4; m; m >>= 1) s += __shfl_xor(s, m);
            float p = (j + sgsel < chunk) ? exp2f(s) : 0.f;
            lden += p;
            _Float16 ph = (_Float16)p;
            h2 p2 = {ph, ph};
            acc2[0] += p2 * U2H(q.x);
            acc2[1] += p2 * U2H(q.y);
            acc2[2] += p2 * U2H(q.z);
            acc2[3] += p2 * U2H(q.w);
        }
        done += chunk;
    }

    #pragma unroll
    for (int i = 0; i < 4; i++) {
        u32 o = (u32)__shfl_xor((int)H2Ub(acc2[i]), 16);
        acc2[i] = acc2[i] + U2H(o);
    }
    lden += __shfl_xor(lden, 16);

    float rl = 1.f / fmaxf(lden, 1e-30f);
    if (!(l & 16)) {
        float4 b0 = *(const float4*)(bias + ch0);
        float4 b1 = *(const float4*)(bias + ch0 + 4);
        uint4 w;
        w.x = (u32)f2h((float)acc2[0][0] * rl + b0.x) |
              ((u32)f2h((float)acc2[0][1] * rl + b0.y) << 16);
        w.y = (u32)f2h((float)acc2[1][0] * rl + b0.z) |
              ((u32)f2h((float)acc2[1][1] * rl + b0.w) << 16);
        w.z = (u32)f2h((float)acc2[2][0] * rl + b1.x) |
              ((u32)f2h((float)acc2[2][1] * rl + b1.y) << 16);
        w.w = (u32)f2h((float)acc2[3][0] * rl + b1.z) |
              ((u32)f2h((float)acc2[3][1] * rl + b1.w) << 16);
        *(uint4*)&sAggU[half * 64 + g16 * 4] = w;
    }
    asm volatile("s_waitcnt lgkmcnt(0)" ::: "memory");   // same-wave DS visibility

    float h0 = bf[hl], h1 = bf[hl + 32];
    #pragma unroll 8
    for (int k4 = 0; k4 < 32; k4++) {
        uint4 wp = sWp[k4 * 32 + hl];
        uint2 ag = *(const uint2*)&sAggU[half * 64 + k4 * 2];
        h0 = fdot2f(U2H(ag.x), U2H(wp.x), h0);
        h0 = fdot2f(U2H(ag.y), U2H(wp.y), h0);
        h1 = fdot2f(U2H(ag.x), U2H(wp.z), h1);
        h1 = fdot2f(U2H(ag.y), U2H(wp.w), h1);
    }

    float s1r = h0 + h1, s2r = h0 * h0 + h1 * h1;
    #pragma unroll
    for (int m = 16; m; m >>= 1) { s1r += __shfl_xor(s1r, m); s2r += __shfl_xor(s2r, m); }
    float mu  = s1r * (1.f / 64.f);
    float var = s2r * (1.f / 64.f) - mu * mu;
    float rs  = rsqrtf(fmaxf(var, 0.f) + 1e-5f);
    if (active) {
        out[(size_t)n * DOUT + hl]      = (h0 - mu) * rs * gamma[hl]      + beta[hl];
        out[(size_t)n * DOUT + hl + 32] = (h1 - mu) * rs * gamma[hl + 32] + beta[hl + 32];
    }
}

// ---------------------------------------------------------------------------
// Cooperative persistent kernel: all phases, grid.sync between.
// ---------------------------------------------------------------------------
__global__ __launch_bounds__(256) void fused_all(
    const float* X, const int* E, const float* attr,
    const float* Wl, const float* bl, const float* Wr, const float* br,
    const float* att, const float* bias, const float* Wf, const float* bf,
    const float* gamma, const float* beta,
    int* count, u16* bucket, u16* xl_p, u16* xr_p,
    u16* WTl, u16* WTr, uint4* Wfp, float* out,
    int N, int NE, int GB)
{
    __shared__ SharedU sh;
    const int tid  = threadIdx.x;
    const int bid  = blockIdx.x;
    const int nB   = gridDim.x;
    const int gsz  = nB * 256;
    const int gtid = bid * 256 + tid;

    // ---- phase 0: prep ----
    for (int i = gtid; i < N + 33792; i += gsz)
        dev_prep_item(i, Wl, Wr, Wf, WTl, WTr, Wfp, count, N);

    cg::this_grid().sync();

    // ---- phase 1: GEMM tiles + scatter + passthrough, alternating roles ----
    const int TT = 2 * GB;
    if (bid & 1) {
        for (int bt = bid; bt < TT; bt += nB)
            dev_gemm_tile(bt, tid, sh.sX, X, WTl, bl, WTr, br, xl_p, xr_p, N);
        for (int e = gtid; e < NE; e += gsz)
            dev_scatter_edge(e, E, count, bucket, N, NE);
    } else {
        for (int e = gtid; e < NE; e += gsz)
            dev_scatter_edge(e, E, count, bucket, N, NE);
        for (int bt = bid; bt < TT; bt += nB)
            dev_gemm_tile(bt, tid, sh.sX, X, WTl, bl, WTr, br, xl_p, xr_p, N);
    }
    {
        const size_t base = (size_t)N * DOUT;
        for (int p = gtid; p < 3 * NE; p += gsz)
            dev_pass_item(p, E, attr, out, base, NE);
    }

    cg::this_grid().sync();

    // ---- phase 2: edge softmax-aggregate + final linear + LayerNorm ----
    for (int idx = tid; idx < 1024; idx += 256) sh.ef.sWp[idx] = Wfp[idx];
    __syncthreads();
    const int ngroups = (N + 7) / 8;
    for (int g = bid; g < ngroups; g += nB)
        dev_edge_group(g, tid, sh.ef.sWp, sh.ef.sAggU,
                       xl_p, xr_p, att, bias, bf, gamma, beta,
                       count, bucket, out, N);
}

// ---------------------------------------------------------------------------
// Fallback (non-cooperative) kernels — same device code, 3 launches.
// ---------------------------------------------------------------------------
__global__ void k_prep(const float* __restrict__ Wl, const float* __restrict__ Wr,
                       const float* __restrict__ Wf, u16* __restrict__ WTl,
                       u16* __restrict__ WTr, uint4* __restrict__ Wfp,
                       int* __restrict__ count, int N)
{
    int i = blockIdx.x * 256 + threadIdx.x;
    if (i < N + 33792) dev_prep_item(i, Wl, Wr, Wf, WTl, WTr, Wfp, count, N);
}

__global__ __launch_bounds__(256) void k_work(
    const float* X, const int* E, const float* attr,
    const u16* WTl, const float* bl, const u16* WTr, const float* br,
    int* count, u16* bucket, u16* xl_p, u16* xr_p, float* out,
    int N, int NE, int GB)
{
    __shared__ SharedU sh;
    const int tid  = threadIdx.x;
    const int bid  = blockIdx.x;
    const int nB   = gridDim.x;
    const int gsz  = nB * 256;
    const int gtid = bid * 256 + tid;
    const int TT = 2 * GB;
    if (bid & 1) {
        for (int bt = bid; bt < TT; bt += nB)
            dev_gemm_tile(bt, tid, sh.sX, X, WTl, bl, WTr, br, xl_p, xr_p, N);
        for (int e = gtid; e < NE; e += gsz)
            dev_scatter_edge(e, E, count, bucket, N, NE);
    } else {
        for (int e = gtid; e < NE; e += gsz)
            dev_scatter_edge(e, E, count, bucket, N, NE);
        for (int bt = bid; bt < TT; bt += nB)
            dev_gemm_tile(bt, tid, sh.sX, X, WTl, bl, WTr, br, xl_p, xr_p, N);
    }
    const size_t base = (size_t)N * DOUT;
    for (int p = gtid; p < 3 * NE; p += gsz)
        dev_pass_item(p, E, attr, out, base, NE);
}

__global__ __launch_bounds__(256, 6) void k_edge(
    const u16* xl_p, const u16* xr_p, const float* att, const float* bias,
    const uint4* Wfp, const float* bf, const float* gamma, const float* beta,
    const int* count, const u16* bucket, float* out, int N)
{
    __shared__ uint4 sWp[1024];
    __shared__ u32   sAggU[8 * 64];
    const int tid = threadIdx.x;
    for (int idx = tid; idx < 1024; idx += 256) sWp[idx] = Wfp[idx];
    __syncthreads();
    dev_edge_group(blockIdx.x, tid, sWp, sAggU, xl_p, xr_p, att, bias,
                   bf, gamma, beta, count, bucket, out, N);
}

// ---------------------------------------------------------------------------
extern "C" void kernel_launch(void* const* d_in, const int* in_sizes, int n_in,
                              void* d_out, int out_size, void* d_ws, size_t ws_size,
                              hipStream_t stream) {
    const float* X    = (const float*)d_in[0];
    const int*   E    = (const int*)d_in[1];
    const float* attr = (const float*)d_in[2];
    const float* Wl   = (const float*)d_in[3];
    const float* bl   = (const float*)d_in[4];
    const float* Wr   = (const float*)d_in[5];
    const float* br   = (const float*)d_in[6];
    const float* att  = (const float*)d_in[7];
    const float* bias = (const float*)d_in[8];
    const float* Wf   = (const float*)d_in[9];
    const float* bf   = (const float*)d_in[10];
    const float* gamma= (const float*)d_in[11];
    const float* beta = (const float*)d_in[12];
    float* out = (float*)d_out;

    int N  = in_sizes[0] / DIN;
    int NE = in_sizes[1] / 2;
    int GB = (N + 63) / 64;

    char* ws = (char*)d_ws;
    int* count      = (int*)ws;               ws += (size_t)N * 4;
    u16* bucket     = (u16*)ws;               ws += (size_t)N * BCAP * 2;
    u16* xl_p       = (u16*)ws;               ws += (size_t)N * HD * 2;
    u16* xr_p       = (u16*)ws;               ws += (size_t)N * HD * 2;
    u16* WTl        = (u16*)ws;               ws += 128 * 128 * 2;
    u16* WTr        = (u16*)ws;               ws += 128 * 128 * 2;
    uint4* Wfp      = (uint4*)ws;             ws += 1024 * 16;

    // cooperative grid sizing (cached; host-only queries, capture-safe)
    static int coopGrid = -2;
    if (coopGrid == -2) {
        int maxB = 0;
        if (hipOccupancyMaxActiveBlocksPerMultiprocessor(
                &maxB, (const void*)fused_all, 256, 0) == hipSuccess && maxB > 0) {
            int dev = 0;
            hipGetDevice(&dev);
            hipDeviceProp_t prop{};
            int nCU = 256;
            if (hipGetDeviceProperties(&prop, dev) == hipSuccess &&
                prop.multiProcessorCount > 0)
                nCU = prop.multiProcessorCount;
            coopGrid = maxB * nCU;
        } else {
            coopGrid = -1;    // cooperative path unavailable
        }
    }

    bool done = false;
    if (coopGrid > 0) {
        void* args[] = {
            (void*)&X, (void*)&E, (void*)&attr,
            (void*)&Wl, (void*)&bl, (void*)&Wr, (void*)&br,
            (void*)&att, (void*)&bias, (void*)&Wf, (void*)&bf,
            (void*)&gamma, (void*)&beta,
            (void*)&count, (void*)&bucket, (void*)&xl_p, (void*)&xr_p,
            (void*)&WTl, (void*)&WTr, (void*)&Wfp, (void*)&out,
            (void*)&N, (void*)&NE, (void*)&GB };
        if (hipLaunchCooperativeKernel((const void*)fused_all,
                dim3(coopGrid), dim3(256), args, 0, stream) == hipSuccess)
            done = true;
    }

    if (!done) {
        k_prep<<<(N + 33792 + 255) / 256, 256, 0, stream>>>(
            Wl, Wr, Wf, WTl, WTr, Wfp, count, N);
        k_work<<<2 * GB, 256, 0, stream>>>(
            X, E, attr, WTl, bl, WTr, br, count, bucket, xl_p, xr_p, out, N, NE, GB);
        k_edge<<<(N + 7) / 8, 256, 0, stream>>>(
            xl_p, xr_p, att, bias, Wfp, bf, gamma, beta, count, bucket, out, N);
    }
}

// Round 11
// 210.358 us; speedup vs baseline: 1.8662x; 1.8662x over previous
//
#include <hip/hip_runtime.h>

typedef unsigned short u16;
typedef unsigned int   u32;

// RESOLVED (rounds 0-10): d_out is FLOAT32. Inputs f32. din=128, hd=128
// (H=2, dout=64), N=in_sizes[0]/128, NE=in_sizes[1]/2.
// Outputs flat f32: H_out [0,N*64) ; E [N*64,+2NE) ; attr [+NE).
// R17: fp16 (absmax .0156). R19: bucket scatter, 219. R20: LB8 regressed
//      (edge_fused is L2-locality-sensitive). R21: gemm+scatter fused 80us
//      but occ 27% (51KB LDS). R22: cooperative single kernel REGRESSED
//      (393): occupancy API sized grid at 3 blocks/CU (64KB LDS budget),
//      all phases TLP-starved. KEY FACT from R22: total - kernel_sum ~65us
//      REGARDLESS of launch count (1, 3, or 4 launches) -> fixed harness
//      overhead, launch-count reduction is NOT a lever. Kernel time only.
// R23: R22's (never-executed) fallback path as plain launches: k_work =
//      scatter + passthrough + GEMM with sX-only LDS (17.4KB), W^T from
//      global (32KB, L1-hot). LDS cap 3 -> ~7 blocks/CU: scatter TLP
//      restored, global-W latency hidden, sW bank conflicts gone.

#define DIN   128
#define DOUT  64
#define HD    128   // H * DOUT
#define BCAP  64    // bucket capacity per node

typedef __attribute__((ext_vector_type(8))) _Float16 f16x8;
typedef __attribute__((ext_vector_type(2))) _Float16 h2;
typedef __attribute__((ext_vector_type(4))) float    f32x4;

union H2U { u32 u; h2 h; };
__device__ __forceinline__ h2  U2H(u32 u) { H2U x; x.u = u; return x.h; }
__device__ __forceinline__ u32 H2Ub(h2 h) { H2U x; x.h = h; return x.u; }

__device__ __forceinline__ u16 f2h(float f) {
    _Float16 h = (_Float16)f;              // RNE
    u16 r; __builtin_memcpy(&r, &h, 2); return r;
}

// packed fp16 max via ISA (v_pk_max_f16 is VOP3P, present on gfx950)
__device__ __forceinline__ u32 pkmax(u32 a, u32 b) {
    u32 d;
    asm("v_pk_max_f16 %0, %1, %2" : "=v"(d) : "v"(a), "v"(b));
    return d;
}

__device__ __forceinline__ float fdot2f(h2 a, h2 b, float c) {
#if __has_builtin(__builtin_amdgcn_fdot2)
    return __builtin_amdgcn_fdot2(a, b, c, false);
#else
    return c + (float)a[0] * (float)b[0] + (float)a[1] * (float)b[1];
#endif
}

// ---------------------------------------------------------------------------
// phase-0 item: zero count + WT transpose->fp16 + Wfp pack
// ---------------------------------------------------------------------------
__device__ __forceinline__ void dev_prep_item(
    int i, const float* __restrict__ Wl, const float* __restrict__ Wr,
    const float* __restrict__ Wf, u16* __restrict__ WTl, u16* __restrict__ WTr,
    uint4* __restrict__ Wfp, int* __restrict__ count, int N)
{
    if (i < N) { count[i] = 0; return; }
    int j = i - N;
    if (j < 16384) {
        int k = j >> 7, c = j & 127;
        WTl[c * 128 + k] = f2h(Wl[j]);
    } else if (j < 32768) {
        int t = j - 16384;
        int k = t >> 7, c = t & 127;
        WTr[c * 128 + k] = f2h(Wr[t]);
    } else if (j < 33792) {
        int t = j - 32768;
        int k4 = t >> 5, c = t & 31;
        const float* wrow = Wf + (size_t)(4 * k4) * DOUT;
        u32 a0 = (u32)f2h(wrow[c])              | ((u32)f2h(wrow[DOUT + c]) << 16);
        u32 a1 = (u32)f2h(wrow[2 * DOUT + c])   | ((u32)f2h(wrow[3 * DOUT + c]) << 16);
        u32 a2 = (u32)f2h(wrow[c + 32])         | ((u32)f2h(wrow[DOUT + c + 32]) << 16);
        u32 a3 = (u32)f2h(wrow[2 * DOUT + c + 32]) | ((u32)f2h(wrow[3 * DOUT + c + 32]) << 16);
        Wfp[t] = make_uint4(a0, a1, a2, a3);
    }
}

__global__ void k_prep(const float* __restrict__ Wl, const float* __restrict__ Wr,
                       const float* __restrict__ Wf, u16* __restrict__ WTl,
                       u16* __restrict__ WTr, uint4* __restrict__ Wfp,
                       int* __restrict__ count, int N)
{
    int i = blockIdx.x * 256 + threadIdx.x;
    if (i < N + 33792) dev_prep_item(i, Wl, Wr, Wf, WTl, WTr, Wfp, count, N);
}

// ---------------------------------------------------------------------------
// K1: k_work = bucket scatter + E/attr passthrough + MFMA GEMM.
// Grid = 2*GB blocks; cb = bid&1, tile row0 = (bid>>1)*64. Alternating
// roles by bid parity: half the blocks gemm-first, half scatter-first ->
// heterogeneous co-residency (atomic latency hides under MFMA).
// GEMM: A = W^T from GLOBAL (32KB, L1-hot after first touch), B = X via
// LDS (17.4KB only -> ~7 blocks/CU). D col=node, row=c -> uint2 stores.
// ---------------------------------------------------------------------------
__device__ __forceinline__ void dev_scatter_edge(
    int e, const int* __restrict__ E, int* __restrict__ count,
    u16* __restrict__ bucket, int N, int NE)
{
    int src = E[e];
    int dst = E[NE + e];
    if ((u32)dst >= (u32)N) dst = 0;
    if ((u32)src >= (u32)N) src = 0;
    int rank = atomicAdd(&count[dst], 1);
    if (rank < BCAP) bucket[(size_t)dst * BCAP + rank] = (u16)src;
}

__device__ __forceinline__ void dev_gemm_tile(
    int bt, int tid, u16* sX,
    const float* __restrict__ X,
    const u16* __restrict__ WTl, const float* __restrict__ bl,
    const u16* __restrict__ WTr, const float* __restrict__ br,
    u16* __restrict__ xl_p, u16* __restrict__ xr_p, int N)
{
    const int cb   = bt & 1;
    const int row0 = (bt >> 1) * 64;
    const u16*   WT  = cb ? WTr : WTl;
    const float* bia = cb ? br : bl;

    for (int idx = tid; idx < 64 * 32; idx += 256) {
        int r  = idx >> 5;
        int k4 = (idx & 31) << 2;
        int gr = row0 + r;
        float4 v = make_float4(0.f, 0.f, 0.f, 0.f);
        if (gr < N) v = *(const float4*)(X + (size_t)gr * DIN + k4);
        u32 p0 = (u32)f2h(v.x) | ((u32)f2h(v.y) << 16);
        u32 p1 = (u32)f2h(v.z) | ((u32)f2h(v.w) << 16);
        *(uint2*)&sX[r * 136 + k4] = make_uint2(p0, p1);
    }
    __syncthreads();

    const int wv   = tid >> 6;
    const int lane = tid & 63;
    const int m    = lane & 15;
    const int quad = lane >> 4;

    f32x4 acc[8] = {};
    #pragma unroll
    for (int kc = 0; kc < 4; kc++) {
        f16x8 bx = *(const f16x8*)&sX[(wv * 16 + m) * 136 + kc * 32 + quad * 8];
        #pragma unroll
        for (int t = 0; t < 8; t++) {
            f16x8 aw = *(const f16x8*)&WT[(t * 16 + m) * 128 + kc * 32 + quad * 8];
            acc[t] = __builtin_amdgcn_mfma_f32_16x16x32_f16(aw, bx, acc[t], 0, 0, 0);
        }
    }

    const int gn = row0 + wv * 16 + m;          // node (D col = lane&15)
    if (gn < N) {
        u16* dst = cb ? xr_p : xl_p;
        #pragma unroll
        for (int t = 0; t < 8; t++) {
            const int c0 = t * 16 + quad * 4;   // D row = quad*4+r
            float4 bv = *(const float4*)(bia + c0);
            u32 p0 = (u32)f2h(acc[t][0] + bv.x) | ((u32)f2h(acc[t][1] + bv.y) << 16);
            u32 p1 = (u32)f2h(acc[t][2] + bv.z) | ((u32)f2h(acc[t][3] + bv.w) << 16);
            *(uint2*)(dst + (size_t)gn * HD + c0) = make_uint2(p0, p1);
        }
    }
}

__global__ __launch_bounds__(256) void k_work(
    const float* __restrict__ X, const int* __restrict__ E,
    const float* __restrict__ attr,
    const u16* __restrict__ WTl, const float* __restrict__ bl,
    const u16* __restrict__ WTr, const float* __restrict__ br,
    int* __restrict__ count, u16* __restrict__ bucket,
    u16* __restrict__ xl_p, u16* __restrict__ xr_p,
    float* __restrict__ out, int N, int NE, int GB)
{
    __shared__ u16 sX[64 * 136];    // 17408 B — only LDS in this kernel
    const int tid  = threadIdx.x;
    const int bid  = blockIdx.x;
    const int nB   = gridDim.x;
    const int gsz  = nB * 256;
    const int gtid = bid * 256 + tid;
    const int TT   = 2 * GB;

    if (bid & 1) {
        for (int bt = bid; bt < TT; bt += nB)
            dev_gemm_tile(bt, tid, sX, X, WTl, bl, WTr, br, xl_p, xr_p, N);
        for (int e = gtid; e < NE; e += gsz)
            dev_scatter_edge(e, E, count, bucket, N, NE);
    } else {
        for (int e = gtid; e < NE; e += gsz)
            dev_scatter_edge(e, E, count, bucket, N, NE);
        for (int bt = bid; bt < TT; bt += nB)
            dev_gemm_tile(bt, tid, sX, X, WTl, bl, WTr, br, xl_p, xr_p, N);
    }
    const size_t base = (size_t)N * DOUT;
    for (int p = gtid; p < 3 * NE; p += gsz) {
        if (p < 2 * NE) out[base + p] = (float)E[p];
        else            out[base + p] = attr[p - 2 * NE];
    }
}

// ---------------------------------------------------------------------------
// K2: edge softmax-aggregate + final linear + LayerNorm (measured-best
// config: LB(256,6), uint4 gathers, fp16 packed math, u16 bucket).
// ---------------------------------------------------------------------------
template<int D>
__device__ __forceinline__ void edge_block(
    int myidx, int j, int sgbase, const char* xbase,
    const h2* xr2, const h2* at2, h2 c02,
    h2* acc2, float& lden)
{
    uint4 q[D];
    #pragma unroll
    for (int b = 0; b < D; b++) {
        u32 off = (u32)__shfl(myidx, sgbase + j + 2 * b) << 8;
        q[b] = *(const uint4*)(xbase + off);
    }
    float sh[D];
    #pragma unroll
    for (int b = 0; b < D; b++) {
        h2 v0 = U2H(q[b].x) + xr2[0];
        h2 v1 = U2H(q[b].y) + xr2[1];
        h2 v2 = U2H(q[b].z) + xr2[2];
        h2 v3 = U2H(q[b].w) + xr2[3];
        v0 = U2H(pkmax(H2Ub(v0), H2Ub(v0 * c02)));
        v1 = U2H(pkmax(H2Ub(v1), H2Ub(v1 * c02)));
        v2 = U2H(pkmax(H2Ub(v2), H2Ub(v2 * c02)));
        v3 = U2H(pkmax(H2Ub(v3), H2Ub(v3 * c02)));
        float s = fdot2f(v0, at2[0], 0.f);
        s = fdot2f(v1, at2[1], s);
        s = fdot2f(v2, at2[2], s);
        s = fdot2f(v3, at2[3], s);
        sh[b] = s;
    }
    #pragma unroll
    for (int m = 4; m; m >>= 1) {
        #pragma unroll
        for (int b = 0; b < D; b++) sh[b] += __shfl_xor(sh[b], m);
    }
    #pragma unroll
    for (int b = 0; b < D; b++) {
        float p = exp2f(sh[b]);
        lden += p;
        _Float16 ph = (_Float16)p;
        h2 p2 = {ph, ph};
        acc2[0] += p2 * U2H(q[b].x);
        acc2[1] += p2 * U2H(q[b].y);
        acc2[2] += p2 * U2H(q[b].z);
        acc2[3] += p2 * U2H(q[b].w);
    }
}

__global__ __launch_bounds__(256, 6) void k_edge(
    const u16* __restrict__ xl_p, const u16* __restrict__ xr_p,
    const float* __restrict__ att, const float* __restrict__ bias,
    const uint4* __restrict__ Wfp, const float* __restrict__ bf,
    const float* __restrict__ gamma, const float* __restrict__ beta,
    const int* __restrict__ count, const u16* __restrict__ bucket,
    float* __restrict__ out, int N)
{
    __shared__ uint4 sWp[1024];         // 16 KB packed fp16 Wf
    __shared__ u32   sAggU[8 * 64];     // 2 KB

    const int tid = threadIdx.x;
    for (int idx = tid; idx < 1024; idx += 256) sWp[idx] = Wfp[idx];
    __syncthreads();

    const int l      = tid & 63;
    const int half   = tid >> 5;
    const int hl     = tid & 31;
    const int g16    = l & 15;
    const int ch0    = g16 * 8;
    const int sgsel  = (l >> 4) & 1;
    const int sgbase = (l & 32) + sgsel;
    const int n      = blockIdx.x * 8 + half;
    const bool active = (n < N);

    const h2 c02 = {(_Float16)0.2f, (_Float16)0.2f};
    h2 at2[4], xr2[4];
    {
        const float L2E = 1.44269504f;
        float4 a0 = *(const float4*)(att + ch0);
        float4 a1 = *(const float4*)(att + ch0 + 4);
        at2[0] = h2{(_Float16)(a0.x * L2E), (_Float16)(a0.y * L2E)};
        at2[1] = h2{(_Float16)(a0.z * L2E), (_Float16)(a0.w * L2E)};
        at2[2] = h2{(_Float16)(a1.x * L2E), (_Float16)(a1.y * L2E)};
        at2[3] = h2{(_Float16)(a1.z * L2E), (_Float16)(a1.w * L2E)};
        uint4 pr = make_uint4(0, 0, 0, 0);
        if (active) pr = *(const uint4*)(xr_p + (size_t)n * HD + ch0);
        xr2[0] = U2H(pr.x); xr2[1] = U2H(pr.y);
        xr2[2] = U2H(pr.z); xr2[3] = U2H(pr.w);
    }

    h2 acc2[4] = {};
    float lden = 0.f;

    int cnt_b = 0;
    if (active) {
        cnt_b = count[n];
        if (cnt_b < 0) cnt_b = 0;
        if (cnt_b > BCAP) cnt_b = BCAP;
    }
    const int cnt = active ? cnt_b + 1 : 0;   // + virtual self loop
    const u16* mybkt = bucket + (size_t)(active ? n : 0) * BCAP;

    const char* xbase = (const char*)xl_p + ch0 * 2;

    int done = 0;
    while (done < cnt) {
        int chunk = cnt - done; if (chunk > 32) chunk = 32;
        int myidx = 0;
        if (hl < chunk) {
            int gj = done + hl;
            myidx = (gj < cnt_b) ? (int)mybkt[gj] : n;
        }
        int j = 0;
        for (; j + 16 <= chunk; j += 16)
            edge_block<8>(myidx, j, sgbase, xbase, xr2, at2, c02, acc2, lden);
        if (j + 8 <= chunk) {
            edge_block<4>(myidx, j, sgbase, xbase, xr2, at2, c02, acc2, lden);
            j += 8;
        }
        if (j + 4 <= chunk) {
            edge_block<2>(myidx, j, sgbase, xbase, xr2, at2, c02, acc2, lden);
            j += 4;
        }
        for (; j < chunk; j += 2) {
            u32 off = (u32)__shfl(myidx, sgbase + j) << 8;
            uint4 q = *(const uint4*)(xbase + off);
            h2 v0 = U2H(q.x) + xr2[0];
            h2 v1 = U2H(q.y) + xr2[1];
            h2 v2 = U2H(q.z) + xr2[2];
            h2 v3 = U2H(q.w) + xr2[3];
            v0 = U2H(pkmax(H2Ub(v0), H2Ub(v0 * c02)));
            v1 = U2H(pkmax(H2Ub(v1), H2Ub(v1 * c02)));
            v2 = U2H(pkmax(H2Ub(v2), H2Ub(v2 * c02)));
            v3 = U2H(pkmax(H2Ub(v3), H2Ub(v3 * c02)));
            float s = fdot2f(v0, at2[0], 0.f);
            s = fdot2f(v1, at2[1], s);
            s = fdot2f(v2, at2[2], s);
            s = fdot2f(v3, at2[3], s);
            #pragma unroll
            for (int m = 4; m; m >>= 1) s += __shfl_xor(s, m);
            float p = (j + sgsel < chunk) ? exp2f(s) : 0.f;
            lden += p;
            _Float16 ph = (_Float16)p;
            h2 p2 = {ph, ph};
            acc2[0] += p2 * U2H(q.x);
            acc2[1] += p2 * U2H(q.y);
            acc2[2] += p2 * U2H(q.z);
            acc2[3] += p2 * U2H(q.w);
        }
        done += chunk;
    }

    #pragma unroll
    for (int i = 0; i < 4; i++) {
        u32 o = (u32)__shfl_xor((int)H2Ub(acc2[i]), 16);
        acc2[i] = acc2[i] + U2H(o);
    }
    lden += __shfl_xor(lden, 16);

    float rl = 1.f / fmaxf(lden, 1e-30f);
    if (!(l & 16)) {
        float4 b0 = *(const float4*)(bias + ch0);
        float4 b1 = *(const float4*)(bias + ch0 + 4);
        uint4 w;
        w.x = (u32)f2h((float)acc2[0][0] * rl + b0.x) |
              ((u32)f2h((float)acc2[0][1] * rl + b0.y) << 16);
        w.y = (u32)f2h((float)acc2[1][0] * rl + b0.z) |
              ((u32)f2h((float)acc2[1][1] * rl + b0.w) << 16);
        w.z = (u32)f2h((float)acc2[2][0] * rl + b1.x) |
              ((u32)f2h((float)acc2[2][1] * rl + b1.y) << 16);
        w.w = (u32)f2h((float)acc2[3][0] * rl + b1.z) |
              ((u32)f2h((float)acc2[3][1] * rl + b1.w) << 16);
        *(uint4*)&sAggU[half * 64 + g16 * 4] = w;
    }
    asm volatile("s_waitcnt lgkmcnt(0)" ::: "memory");   // same-wave DS visibility

    float h0 = bf[hl], h1 = bf[hl + 32];
    #pragma unroll 8
    for (int k4 = 0; k4 < 32; k4++) {
        uint4 wp = sWp[k4 * 32 + hl];
        uint2 ag = *(const uint2*)&sAggU[half * 64 + k4 * 2];
        h0 = fdot2f(U2H(ag.x), U2H(wp.x), h0);
        h0 = fdot2f(U2H(ag.y), U2H(wp.y), h0);
        h1 = fdot2f(U2H(ag.x), U2H(wp.z), h1);
        h1 = fdot2f(U2H(ag.y), U2H(wp.w), h1);
    }

    float s1r = h0 + h1, s2r = h0 * h0 + h1 * h1;
    #pragma unroll
    for (int m = 16; m; m >>= 1) { s1r += __shfl_xor(s1r, m); s2r += __shfl_xor(s2r, m); }
    float mu  = s1r * (1.f / 64.f);
    float var = s2r * (1.f / 64.f) - mu * mu;
    float rs  = rsqrtf(fmaxf(var, 0.f) + 1e-5f);
    if (active) {
        out[(size_t)n * DOUT + hl]      = (h0 - mu) * rs * gamma[hl]      + beta[hl];
        out[(size_t)n * DOUT + hl + 32] = (h1 - mu) * rs * gamma[hl + 32] + beta[hl + 32];
    }
}

// ---------------------------------------------------------------------------
extern "C" void kernel_launch(void* const* d_in, const int* in_sizes, int n_in,
                              void* d_out, int out_size, void* d_ws, size_t ws_size,
                              hipStream_t stream) {
    const float* X    = (const float*)d_in[0];
    const int*   E    = (const int*)d_in[1];
    const float* attr = (const float*)d_in[2];
    const float* Wl   = (const float*)d_in[3];
    const float* bl   = (const float*)d_in[4];
    const float* Wr   = (const float*)d_in[5];
    const float* br   = (const float*)d_in[6];
    const float* att  = (const float*)d_in[7];
    const float* bias = (const float*)d_in[8];
    const float* Wf   = (const float*)d_in[9];
    const float* bf   = (const float*)d_in[10];
    const float* gamma= (const float*)d_in[11];
    const float* beta = (const float*)d_in[12];
    float* out = (float*)d_out;

    const int N  = in_sizes[0] / DIN;
    const int NE = in_sizes[1] / 2;
    const int GB = (N + 63) / 64;

    char* ws = (char*)d_ws;
    int* count      = (int*)ws;               ws += (size_t)N * 4;
    u16* bucket     = (u16*)ws;               ws += (size_t)N * BCAP * 2;
    u16* xl_p       = (u16*)ws;               ws += (size_t)N * HD * 2;
    u16* xr_p       = (u16*)ws;               ws += (size_t)N * HD * 2;
    u16* WTl        = (u16*)ws;               ws += 128 * 128 * 2;
    u16* WTr        = (u16*)ws;               ws += 128 * 128 * 2;
    uint4* Wfp      = (uint4*)ws;             ws += 1024 * 16;

    k_prep<<<(N + 33792 + 255) / 256, 256, 0, stream>>>(
        Wl, Wr, Wf, WTl, WTr, Wfp, count, N);

    k_work<<<2 * GB, 256, 0, stream>>>(
        X, E, attr, WTl, bl, WTr, br, count, bucket, xl_p, xr_p, out, N, NE, GB);

    k_edge<<<(N + 7) / 8, 256, 0, stream>>>(
        xl_p, xr_p, att, bias, Wfp, bf, gamma, beta, count, bucket, out, N);
}